// Round 9
// baseline (72.018 us; speedup 1.0000x reference)
//
#include <hip/hip_runtime.h>
#include <math.h>
#include <stdint.h>

#define NB  64
#define NT  512
#define ND  1024
#define NVT 6
#define NVY 20
#define TYPE_PAD_V 19
#define NE  2048
#define LOG2E 1.44269504088896340736f
#define LN2   0.69314718055994530942f

typedef float v2f __attribute__((ext_vector_type(2)));

// ws layout (floats):
//   featsT @ 0        : 512*384 = 196608   [t][b][6]
//   WtT    @ 196608   : 20*1024 = 20480    [v][d]
//   cnt    @ 217088   : 16 (counter + pad)
//   ws2    @ 217104   : 32*6*64*8 = 98304  chunk columns
#define OFF_WTT 196608
#define OFF_CNT 217088
#define OFF_WS2 217104

// ---- K1: featsT = H @ W_tag + b_tag. W_tag register-resident, no LDS. ----
__global__ __launch_bounds__(256) void k1_tagfeats(const float* __restrict__ H,
                                                   const float* __restrict__ W_tag,
                                                   const float* __restrict__ b_tag,
                                                   const float* __restrict__ W_type,
                                                   float* __restrict__ ws,
                                                   float* __restrict__ out) {
    float* featsT = ws;
    float* WtT    = ws + OFF_WTT;
    if (blockIdx.x == 0) {
        if (threadIdx.x < NB) out[threadIdx.x] = 0.0f;
        if (threadIdx.x == 64) ((int*)(ws + OFF_CNT))[0] = 0;
    }
    if (blockIdx.x < 32) {
        int tid = blockIdx.x * 256 + threadIdx.x;
        for (int i = tid; i < NVY * ND; i += 32 * 256)
            WtT[i] = W_type[(i & (ND - 1)) * NVY + (i >> 10)];
    }

    const int lane = threadIdx.x & 63;
    const int w    = threadIdx.x >> 6;
    // lane's weights: rows d = 4*lane + 256*k + j (j=0..3), all 6 v. 96 floats.
    float wk[4][24];
    const float4* wt4 = (const float4*)W_tag;
#pragma unroll
    for (int k = 0; k < 4; ++k) {
#pragma unroll
        for (int m = 0; m < 6; ++m) {
            float4 t = wt4[lane * 6 + k * 384 + m];
            wk[k][4 * m + 0] = t.x; wk[k][4 * m + 1] = t.y;
            wk[k][4 * m + 2] = t.z; wk[k][4 * m + 3] = t.w;
        }
    }
    float bt0 = b_tag[0], bt1 = b_tag[1], bt2 = b_tag[2],
          bt3 = b_tag[3], bt4 = b_tag[4], bt5 = b_tag[5];

    const int rbase = blockIdx.x * 32 + w * 8;
    const float4* hr = (const float4*)H + (size_t)rbase * 256;
    float4 h0 = hr[lane], h1 = hr[lane + 64], h2 = hr[lane + 128], h3 = hr[lane + 192];
#pragma unroll
    for (int i = 0; i < 8; ++i) {
        float4 g0, g1, g2, g3;
        if (i < 7) {
            const float4* nr = hr + (size_t)(i + 1) * 256;
            g0 = nr[lane]; g1 = nr[lane + 64]; g2 = nr[lane + 128]; g3 = nr[lane + 192];
        }
        float a0 = 0.f, a1 = 0.f, a2 = 0.f, a3 = 0.f, a4 = 0.f, a5 = 0.f;
#pragma unroll
        for (int k = 0; k < 4; ++k) {
            float4 h = (k == 0) ? h0 : (k == 1) ? h1 : (k == 2) ? h2 : h3;
            a0 = __builtin_fmaf(h.x, wk[k][0],  a0);
            a1 = __builtin_fmaf(h.x, wk[k][1],  a1);
            a2 = __builtin_fmaf(h.x, wk[k][2],  a2);
            a3 = __builtin_fmaf(h.x, wk[k][3],  a3);
            a4 = __builtin_fmaf(h.x, wk[k][4],  a4);
            a5 = __builtin_fmaf(h.x, wk[k][5],  a5);
            a0 = __builtin_fmaf(h.y, wk[k][6],  a0);
            a1 = __builtin_fmaf(h.y, wk[k][7],  a1);
            a2 = __builtin_fmaf(h.y, wk[k][8],  a2);
            a3 = __builtin_fmaf(h.y, wk[k][9],  a3);
            a4 = __builtin_fmaf(h.y, wk[k][10], a4);
            a5 = __builtin_fmaf(h.y, wk[k][11], a5);
            a0 = __builtin_fmaf(h.z, wk[k][12], a0);
            a1 = __builtin_fmaf(h.z, wk[k][13], a1);
            a2 = __builtin_fmaf(h.z, wk[k][14], a2);
            a3 = __builtin_fmaf(h.z, wk[k][15], a3);
            a4 = __builtin_fmaf(h.z, wk[k][16], a4);
            a5 = __builtin_fmaf(h.z, wk[k][17], a5);
            a0 = __builtin_fmaf(h.w, wk[k][18], a0);
            a1 = __builtin_fmaf(h.w, wk[k][19], a1);
            a2 = __builtin_fmaf(h.w, wk[k][20], a2);
            a3 = __builtin_fmaf(h.w, wk[k][21], a3);
            a4 = __builtin_fmaf(h.w, wk[k][22], a4);
            a5 = __builtin_fmaf(h.w, wk[k][23], a5);
        }
#pragma unroll
        for (int off = 32; off >= 1; off >>= 1) {
            a0 += __shfl_xor(a0, off);
            a1 += __shfl_xor(a1, off);
            a2 += __shfl_xor(a2, off);
            a3 += __shfl_xor(a3, off);
            a4 += __shfl_xor(a4, off);
            a5 += __shfl_xor(a5, off);
        }
        float val = a0 + bt0;
        val = (lane == 1) ? a1 + bt1 : val;
        val = (lane == 2) ? a2 + bt2 : val;
        val = (lane == 3) ? a3 + bt3 : val;
        val = (lane == 4) ? a4 + bt4 : val;
        val = (lane == 5) ? a5 + bt5 : val;
        const int r = rbase + i;
        if (lane < 6)
            featsT[(size_t)(r & (NT - 1)) * 384 + (r >> 9) * 6 + lane] = val;
        h0 = g0; h1 = g1; h2 = g2; h3 = g3;
    }
}

// ---- K2: chunks(0..191, fan-in combine) + gold(192..255) + entities(256..) ----
#define LOADC(BUF, c) do {                                                   \
    _Pragma("unroll")                                                        \
    for (int kk = 0; kk < 6; ++kk) {                                         \
        const float4* p = src4 + (size_t)((c) * 6 + kk) * 128;               \
        BUF[2 * kk] = p[0]; BUF[2 * kk + 1] = p[1];                          \
    }                                                                        \
} while (0)

#define CBODY(BUF, c) do {                                                   \
    float i0 = BUF[1].z, i1 = BUF[3].z, i2 = BUF[5].z,                       \
          i3 = BUF[7].z, i4 = BUF[9].z, i5 = BUF[11].z;                      \
    float im = fmaxf(fmaxf(fmaxf(i0, i1), i2), fmaxf(fmaxf(i3, i4), i5));    \
    float w0 = q0 * __builtin_amdgcn_exp2f(i0 - im);                         \
    float w1 = q1 * __builtin_amdgcn_exp2f(i1 - im);                         \
    float w2 = q2 * __builtin_amdgcn_exp2f(i2 - im);                         \
    float w3 = q3 * __builtin_amdgcn_exp2f(i3 - im);                         \
    float w4 = q4 * __builtin_amdgcn_exp2f(i4 - im);                         \
    float w5 = q5 * __builtin_amdgcn_exp2f(i5 - im);                         \
    float n0 = BUF[0].x * w0, n1 = BUF[0].y * w0, n2 = BUF[0].z * w0,        \
          n3 = BUF[0].w * w0, n4 = BUF[1].x * w0, n5 = BUF[1].y * w0;        \
    n0 = __builtin_fmaf(BUF[2].x,  w1, n0); n1 = __builtin_fmaf(BUF[2].y,  w1, n1); \
    n2 = __builtin_fmaf(BUF[2].z,  w1, n2); n3 = __builtin_fmaf(BUF[2].w,  w1, n3); \
    n4 = __builtin_fmaf(BUF[3].x,  w1, n4); n5 = __builtin_fmaf(BUF[3].y,  w1, n5); \
    n0 = __builtin_fmaf(BUF[4].x,  w2, n0); n1 = __builtin_fmaf(BUF[4].y,  w2, n1); \
    n2 = __builtin_fmaf(BUF[4].z,  w2, n2); n3 = __builtin_fmaf(BUF[4].w,  w2, n3); \
    n4 = __builtin_fmaf(BUF[5].x,  w2, n4); n5 = __builtin_fmaf(BUF[5].y,  w2, n5); \
    n0 = __builtin_fmaf(BUF[6].x,  w3, n0); n1 = __builtin_fmaf(BUF[6].y,  w3, n1); \
    n2 = __builtin_fmaf(BUF[6].z,  w3, n2); n3 = __builtin_fmaf(BUF[6].w,  w3, n3); \
    n4 = __builtin_fmaf(BUF[7].x,  w3, n4); n5 = __builtin_fmaf(BUF[7].y,  w3, n5); \
    n0 = __builtin_fmaf(BUF[8].x,  w4, n0); n1 = __builtin_fmaf(BUF[8].y,  w4, n1); \
    n2 = __builtin_fmaf(BUF[8].z,  w4, n2); n3 = __builtin_fmaf(BUF[8].w,  w4, n3); \
    n4 = __builtin_fmaf(BUF[9].x,  w4, n4); n5 = __builtin_fmaf(BUF[9].y,  w4, n5); \
    n0 = __builtin_fmaf(BUF[10].x, w5, n0); n1 = __builtin_fmaf(BUF[10].y, w5, n1); \
    n2 = __builtin_fmaf(BUF[10].z, w5, n2); n3 = __builtin_fmaf(BUF[10].w, w5, n3); \
    n4 = __builtin_fmaf(BUF[11].x, w5, n4); n5 = __builtin_fmaf(BUF[11].y, w5, n5); \
    float qmax = fmaxf(fmaxf(fmaxf(n0, n1), n2), fmaxf(fmaxf(n3, n4), n5));  \
    uint32_t eb = __float_as_uint(qmax) >> 23;                               \
    mAcc2 += (float)((int)eb - 126) + im;                                    \
    float ri = __uint_as_float((uint32_t)(253 - eb) << 23);                  \
    q0 = n0 * ri; q1 = n1 * ri; q2 = n2 * ri;                                \
    q3 = n3 * ri; q4 = n4 * ri; q5 = n5 * ri;                                \
    int lc = (c) + 3; if (lc > 31) lc = 31;                                  \
    LOADC(BUF, lc);                                                          \
} while (0)

__global__ __launch_bounds__(64) void k2_fused(
    const float* __restrict__ H,
    const float* __restrict__ b_type,
    const float* __restrict__ crf_start,
    const float* __restrict__ crf_end,
    const float* __restrict__ crf_trans,
    const int* __restrict__ tag_ids,
    const int* __restrict__ seq_lens,
    const int* __restrict__ ent_sid,
    const int* __restrict__ ent_st,
    const int* __restrict__ ent_en,
    const int* __restrict__ ent_ty,
    float* __restrict__ ws,
    float* __restrict__ out) {
    const float* featsT = ws;
    const float* WtT    = ws + OFF_WTT;
    int* cnt            = (int*)(ws + OFF_CNT);
    float* ws2          = ws + OFF_WS2;
    __shared__ int stag[NT];
    __shared__ float trLp[NVT * NVT];
    __shared__ int isLast;
    const int lane = threadIdx.x;

    if (blockIdx.x < 192) {
        // ---------- chunk block: column k of P_c, lane = sample b ----------
        const int c = blockIdx.x / 6;
        const int k = blockIdx.x - 6 * c;
        const int b = lane;
        const int L = seq_lens[b];
        float F[NVT][NVT];
#pragma unroll
        for (int i = 0; i < NVT; ++i)
#pragma unroll
            for (int j = 0; j < NVT; ++j)
                F[i][j] = __builtin_amdgcn_exp2f(crf_trans[i * NVT + j] * LOG2E);
        const char* pf = (const char*)featsT + b * 24;
        v2f Ebuf[16][3];
#pragma unroll
        for (int u = 0; u < 16; ++u) {
            const v2f* p = (const v2f*)(pf + (size_t)(16 * c + 1 + u) * 1536);
            Ebuf[u][0] = p[0]; Ebuf[u][1] = p[1]; Ebuf[u][2] = p[2];
        }
        float v0, v1, v2, v3, v4, v5;
        v0 = (k == 0) ? 1.f : 0.f; v1 = (k == 1) ? 1.f : 0.f; v2 = (k == 2) ? 1.f : 0.f;
        v3 = (k == 3) ? 1.f : 0.f; v4 = (k == 4) ? 1.f : 0.f; v5 = (k == 5) ? 1.f : 0.f;
        int isc = 0;
#pragma unroll
        for (int u = 0; u < 16; ++u) {
            float e0 = __builtin_amdgcn_exp2f(Ebuf[u][0].x * LOG2E);
            float e1 = __builtin_amdgcn_exp2f(Ebuf[u][0].y * LOG2E);
            float e2 = __builtin_amdgcn_exp2f(Ebuf[u][1].x * LOG2E);
            float e3 = __builtin_amdgcn_exp2f(Ebuf[u][1].y * LOG2E);
            float e4 = __builtin_amdgcn_exp2f(Ebuf[u][2].x * LOG2E);
            float e5 = __builtin_amdgcn_exp2f(Ebuf[u][2].y * LOG2E);
            bool ok = (16 * c + 1 + u) < L;
            float g[NVT];
#pragma unroll
            for (int j = 0; j < NVT; ++j) {
                float s = F[0][j] * v0;
                s = __builtin_fmaf(F[1][j], v1, s);
                s = __builtin_fmaf(F[2][j], v2, s);
                s = __builtin_fmaf(F[3][j], v3, s);
                s = __builtin_fmaf(F[4][j], v4, s);
                s = __builtin_fmaf(F[5][j], v5, s);
                g[j] = s;
            }
            v0 = ok ? e0 * g[0] : v0;  v1 = ok ? e1 * g[1] : v1;
            v2 = ok ? e2 * g[2] : v2;  v3 = ok ? e3 * g[3] : v3;
            v4 = ok ? e4 * g[4] : v4;  v5 = ok ? e5 * g[5] : v5;
            if ((u & 3) == 3) {
                float qmax = fmaxf(fmaxf(fmaxf(v0, v1), v2), fmaxf(fmaxf(v3, v4), v5));
                uint32_t eb = __float_as_uint(qmax) >> 23;
                float ri = __uint_as_float((uint32_t)(253 - eb) << 23);
                v0 *= ri; v1 *= ri; v2 *= ri; v3 *= ri; v4 *= ri; v5 *= ri;
                isc += (int)eb - 126;
            }
        }
        float4* dst = (float4*)(ws2 + (((size_t)c * 6 + k) * 64 + b) * 8);
        dst[0] = make_float4(v0, v1, v2, v3);
        dst[1] = make_float4(v4, v5, (float)isc, 0.0f);

        // ---- fan-in: last chunk block performs the combine ----
        __threadfence();
        if (lane == 0) isLast = (atomicAdd(cnt, 1) == 191);
        __syncthreads();
        if (isLast) {
            __threadfence();
            const int b2 = lane;
            float a0[NVT];
#pragma unroll
            for (int j = 0; j < NVT; ++j) a0[j] = crf_start[j] + featsT[b2 * 6 + j];
            float m0 = fmaxf(fmaxf(fmaxf(a0[0], a0[1]), a0[2]),
                             fmaxf(fmaxf(a0[3], a0[4]), a0[5]));
            float q0 = __builtin_amdgcn_exp2f((a0[0] - m0) * LOG2E);
            float q1 = __builtin_amdgcn_exp2f((a0[1] - m0) * LOG2E);
            float q2 = __builtin_amdgcn_exp2f((a0[2] - m0) * LOG2E);
            float q3 = __builtin_amdgcn_exp2f((a0[3] - m0) * LOG2E);
            float q4 = __builtin_amdgcn_exp2f((a0[4] - m0) * LOG2E);
            float q5 = __builtin_amdgcn_exp2f((a0[5] - m0) * LOG2E);
            float mAcc2 = m0 * LOG2E;

            const float4* src4 = (const float4*)ws2 + b2 * 2;
            float4 PB0[12], PB1[12], PB2[12];
            LOADC(PB0, 0); LOADC(PB1, 1); LOADC(PB2, 2);
#pragma unroll 1
            for (int c0 = 0; c0 < 30; c0 += 3) {
                CBODY(PB0, c0);
                CBODY(PB1, c0 + 1);
                CBODY(PB2, c0 + 2);
            }
            CBODY(PB0, 30);
            CBODY(PB1, 31);

            float zs = q0 * __builtin_amdgcn_exp2f(crf_end[0] * LOG2E)
                     + q1 * __builtin_amdgcn_exp2f(crf_end[1] * LOG2E)
                     + q2 * __builtin_amdgcn_exp2f(crf_end[2] * LOG2E)
                     + q3 * __builtin_amdgcn_exp2f(crf_end[3] * LOG2E)
                     + q4 * __builtin_amdgcn_exp2f(crf_end[4] * LOG2E)
                     + q5 * __builtin_amdgcn_exp2f(crf_end[5] * LOG2E);
            float logZ = LN2 * (mAcc2 + __builtin_amdgcn_logf(zs));
            atomicAdd(&out[b2], logZ);
        }
    } else if (blockIdx.x < 192 + NB) {
        // ---------- gold path score ----------
        const int b = blockIdx.x - 192;
        for (int i = lane; i < NT; i += 64) stag[i] = tag_ids[b * NT + i];
        if (lane < NVT * NVT) trLp[lane] = crf_trans[lane];
        __syncthreads();
        const int L = seq_lens[b];
        float g = 0.0f;
#pragma unroll
        for (int k = 0; k < NT / 64; ++k) {
            int t = lane + 64 * k;
            if (t < L) {
                int tg = stag[t];
                g += featsT[(size_t)t * 384 + b * 6 + tg];
                if (t >= 1) g += trLp[stag[t - 1] * NVT + tg];
            }
        }
#pragma unroll
        for (int off = 32; off >= 1; off >>= 1) g += __shfl_xor(g, off);
        if (lane == 0)
            atomicAdd(&out[b], -(g + crf_start[stag[0]] + crf_end[stag[L - 1]]));
    } else {
        // ---------- entity path: one wave per entity, masked unrolled span ----------
        const int e  = blockIdx.x - 192 - NB;
        const int bb = ent_sid[e];
        const int s  = ent_st[e];
        const int en = ent_en[e];
        const int ty = ent_ty[e];
        float4 sv0 = {0,0,0,0}, sv1 = {0,0,0,0}, sv2 = {0,0,0,0}, sv3 = {0,0,0,0};
        const float4* hb = (const float4*)H + ((size_t)bb * NT + s) * 256;
#pragma unroll
        for (int q = 0; q < 8; ++q) {
            float msk = (s + q < en) ? 1.0f : 0.0f;
            const float4* hr = hb + (size_t)q * 256;
            float4 h0 = hr[lane], h1 = hr[lane + 64],
                   h2 = hr[lane + 128], h3 = hr[lane + 192];
            sv0.x = __builtin_fmaf(h0.x, msk, sv0.x); sv0.y = __builtin_fmaf(h0.y, msk, sv0.y);
            sv0.z = __builtin_fmaf(h0.z, msk, sv0.z); sv0.w = __builtin_fmaf(h0.w, msk, sv0.w);
            sv1.x = __builtin_fmaf(h1.x, msk, sv1.x); sv1.y = __builtin_fmaf(h1.y, msk, sv1.y);
            sv1.z = __builtin_fmaf(h1.z, msk, sv1.z); sv1.w = __builtin_fmaf(h1.w, msk, sv1.w);
            sv2.x = __builtin_fmaf(h2.x, msk, sv2.x); sv2.y = __builtin_fmaf(h2.y, msk, sv2.y);
            sv2.z = __builtin_fmaf(h2.z, msk, sv2.z); sv2.w = __builtin_fmaf(h2.w, msk, sv2.w);
            sv3.x = __builtin_fmaf(h3.x, msk, sv3.x); sv3.y = __builtin_fmaf(h3.y, msk, sv3.y);
            sv3.z = __builtin_fmaf(h3.z, msk, sv3.z); sv3.w = __builtin_fmaf(h3.w, msk, sv3.w);
        }
        const float inv = 1.0f / (float)(en - s);
        float f[NVY];
#pragma unroll 4
        for (int v = 0; v < NVY; ++v) {
            const float4* wv = (const float4*)(WtT + v * ND);
            float4 w0 = wv[lane], w1 = wv[lane + 64],
                   w2 = wv[lane + 128], w3 = wv[lane + 192];
            float p = sv0.x * w0.x + sv0.y * w0.y + sv0.z * w0.z + sv0.w * w0.w;
            p = __builtin_fmaf(sv1.x, w1.x, p); p = __builtin_fmaf(sv1.y, w1.y, p);
            p = __builtin_fmaf(sv1.z, w1.z, p); p = __builtin_fmaf(sv1.w, w1.w, p);
            p = __builtin_fmaf(sv2.x, w2.x, p); p = __builtin_fmaf(sv2.y, w2.y, p);
            p = __builtin_fmaf(sv2.z, w2.z, p); p = __builtin_fmaf(sv2.w, w2.w, p);
            p = __builtin_fmaf(sv3.x, w3.x, p); p = __builtin_fmaf(sv3.y, w3.y, p);
            p = __builtin_fmaf(sv3.z, w3.z, p); p = __builtin_fmaf(sv3.w, w3.w, p);
#pragma unroll
            for (int off = 32; off >= 1; off >>= 1) p += __shfl_xor(p, off);
            f[v] = p * inv + b_type[v];
        }
        float mx = -3.0e38f;
#pragma unroll
        for (int v = 0; v < NVY; ++v) mx = fmaxf(mx, f[v]);
        float sum = 0.0f, goldf = 0.0f;
#pragma unroll
        for (int v = 0; v < NVY; ++v) {
            sum += __expf(f[v] - mx);
            if (v == ty) goldf = f[v];
        }
        float lse = mx + __logf(sum);
        if (ty != TYPE_PAD_V && lane == 0) atomicAdd(&out[bb], lse - goldf);
    }
}

extern "C" void kernel_launch(void* const* d_in, const int* in_sizes, int n_in,
                              void* d_out, int out_size, void* d_ws, size_t ws_size,
                              hipStream_t stream) {
    const float* H         = (const float*)d_in[0];
    const float* W_tag     = (const float*)d_in[1];
    const float* b_tag     = (const float*)d_in[2];
    const float* W_type    = (const float*)d_in[3];
    const float* b_type    = (const float*)d_in[4];
    const float* crf_start = (const float*)d_in[5];
    const float* crf_end   = (const float*)d_in[6];
    const float* crf_trans = (const float*)d_in[7];
    const int* tag_ids     = (const int*)d_in[8];
    const int* seq_lens    = (const int*)d_in[9];
    const int* ent_sid     = (const int*)d_in[10];
    const int* ent_st      = (const int*)d_in[11];
    const int* ent_en      = (const int*)d_in[12];
    const int* ent_ty      = (const int*)d_in[13];
    float* out = (float*)d_out;
    float* ws  = (float*)d_ws;

    hipLaunchKernelGGL(k1_tagfeats, dim3(1024), dim3(256), 0, stream,
                       H, W_tag, b_tag, W_type, ws, out);
    hipLaunchKernelGGL(k2_fused, dim3(192 + NB + NE), dim3(64), 0, stream,
                       H, b_type, crf_start, crf_end, crf_trans,
                       tag_ids, seq_lens, ent_sid, ent_st, ent_en, ent_ty, ws, out);
}